// Round 7
// baseline (7170.409 us; speedup 1.0000x reference)
//
#include <hip/hip_runtime.h>
#include <cstddef>
#include <cstdint>

#define kB 16
#define kT 1500
#define kF 80
#define kH 512
#define kGG 1024
#define kM (kB * kT)

typedef int v4i __attribute__((ext_vector_type(4)));

// Serial system-scope poll (round-5 proven): issue + full wait in one step.
// sc0 sc1 bypasses L1+L2, reads LLC truth — placement-independent progress.
__device__ __forceinline__ void poll_issue(const int* p, v4i* v) {
  asm volatile("global_load_dwordx4 %0, %1, off sc0 sc1"
               : "=v"(*v) : "v"(p) : "memory");
}
__device__ __forceinline__ void poll_wait(v4i* v) {
  asm volatile("s_waitcnt vmcnt(0)" : "+v"(*v) :: "memory");
}

// ---------------------------------------------------------------------------
// GEMM: C(M,1024) = A(M,K) @ Bt(1024,K)^T   (all row-major, fp32)
// ---------------------------------------------------------------------------
__global__ __launch_bounds__(256) void gemm_nt_k(
    const float* __restrict__ A, const float* __restrict__ Bt,
    float* __restrict__ C, int K) {
  __shared__ float As[16][68];
  __shared__ float Bs[16][68];
  const int tid = threadIdx.x;
  const int m0 = blockIdx.x * 64;
  const int n0 = blockIdx.y * 64;
  const int tx = tid & 15;
  const int ty = tid >> 4;
  const int r  = tid >> 2;
  const int q  = tid & 3;
  float acc[4][4] = {};
  for (int k0 = 0; k0 < K; k0 += 16) {
    const float4 va = *(const float4*)&A [(size_t)(m0 + r) * K + k0 + q * 4];
    const float4 vb = *(const float4*)&Bt[(size_t)(n0 + r) * K + k0 + q * 4];
    __syncthreads();
    As[q * 4 + 0][r] = va.x; As[q * 4 + 1][r] = va.y;
    As[q * 4 + 2][r] = va.z; As[q * 4 + 3][r] = va.w;
    Bs[q * 4 + 0][r] = vb.x; Bs[q * 4 + 1][r] = vb.y;
    Bs[q * 4 + 2][r] = vb.z; Bs[q * 4 + 3][r] = vb.w;
    __syncthreads();
#pragma unroll
    for (int kk = 0; kk < 16; ++kk) {
      const float4 a = *(const float4*)&As[kk][ty * 4];
      const float4 b = *(const float4*)&Bs[kk][tx * 4];
      acc[0][0] += a.x * b.x; acc[0][1] += a.x * b.y; acc[0][2] += a.x * b.z; acc[0][3] += a.x * b.w;
      acc[1][0] += a.y * b.x; acc[1][1] += a.y * b.y; acc[1][2] += a.y * b.z; acc[1][3] += a.y * b.w;
      acc[2][0] += a.z * b.x; acc[2][1] += a.z * b.y; acc[2][2] += a.z * b.z; acc[2][3] += a.z * b.w;
      acc[3][0] += a.w * b.x; acc[3][1] += a.w * b.y; acc[3][2] += a.w * b.z; acc[3][3] += a.w * b.w;
    }
  }
#pragma unroll
  for (int i = 0; i < 4; ++i) {
    float4 o;
    o.x = acc[i][0]; o.y = acc[i][1]; o.z = acc[i][2]; o.w = acc[i][3];
    *(float4*)&C[(size_t)(m0 + ty * 4 + i) * kGG + n0 + tx * 4] = o;
  }
}

// ---------------------------------------------------------------------------
// LayerNorm over rows of length 1024 (in place)
// ---------------------------------------------------------------------------
__global__ __launch_bounds__(256) void ln_rows(
    float* __restrict__ w, const float* __restrict__ g,
    const float* __restrict__ bb) {
  const int row = blockIdx.x;
  float4* p = (float4*)(w + (size_t)row * kGG);
  const int tid = threadIdx.x;
  float4 v = p[tid];
  float s  = v.x + v.y + v.z + v.w;
  float s2 = v.x * v.x + v.y * v.y + v.z * v.z + v.w * v.w;
#pragma unroll
  for (int off = 32; off >= 1; off >>= 1) {
    s  += __shfl_down(s, off);
    s2 += __shfl_down(s2, off);
  }
  __shared__ float red[8];
  const int lane = tid & 63, wv = tid >> 6;
  if (lane == 0) { red[wv] = s; red[4 + wv] = s2; }
  __syncthreads();
  s  = red[0] + red[1] + red[2] + red[3];
  s2 = red[4] + red[5] + red[6] + red[7];
  const float mu  = s * (1.f / kGG);
  const float var = s2 * (1.f / kGG) - mu * mu;
  const float rs  = rsqrtf(var + 1e-5f);
  const float4 gg = ((const float4*)g)[tid];
  const float4 bv = ((const float4*)bb)[tid];
  v.x = (v.x - mu) * rs * gg.x + bv.x;
  v.y = (v.y - mu) * rs * gg.y + bv.y;
  v.z = (v.z - mu) * rs * gg.z + bv.z;
  v.w = (v.w - mu) * rs * gg.w + bv.w;
  p[tid] = v;
}

// ---------------------------------------------------------------------------
// LiGRU scan, barrier-free producer/consumer (round-5 skeleton + w-loader).
// h >= 0 invariant => sign-bit-set == "not yet written" (hist poisoned 0xFF).
// Roles (wave-granular; branches are exec-skipped so VMEM/vmcnt streams stay
// disjoint per wave):
//   waves 0-1 (tid 0..127)   : pollers — serial system-scope dwordx4 poll of
//                              h(t-1) (r5-proven issue+wait(0) loop), staged
//                              to padded LDS.
//   wave 2    (tid 128..191) : w-loaders — prefetch w(t+1) one step ahead
//                              into a register, deliver w(t) via tiny LDS
//                              double buffer (w latency off the chain).
//   all threads              : dot over their 64-float LDS slice; ks==0 lanes
//                              finish gates and publish h (agent-scope store).
// ---------------------------------------------------------------------------
__global__ __launch_bounds__(256, 1) void ligru_scan(
    const float* __restrict__ wn,   // (B*T, 1024) normalized pre-gates
    const float* __restrict__ U,    // (1024, 512)
    float* __restrict__ hist) {     // (B, T, 512) h history == layer output
  const int blk  = blockIdx.x;
  const int b    = blk & 15;     // XCD-colocating decode (heuristic only)
  const int jblk = blk >> 4;
  const int tid  = threadIdx.x;
  const int ks   = tid & 7;
  const int jj   = tid >> 3;
  const int j    = jblk * 32 + jj;
  const int k0   = ks * 64;

  __shared__ float hsh[2][8 * 68];   // stride 68 -> conflict-free b128 reads
  __shared__ float wsh[2][64];       // w double buffer (a: 0..31, z: 32..63)

  // ---- U slice pinned in registers ----
  float4 ua[16], uz[16];
#pragma unroll
  for (int q = 0; q < 16; ++q) {
    ua[q] = *(const float4*)&U[(size_t)j * kH + k0 + q * 4];
    uz[q] = *(const float4*)&U[(size_t)(j + kH) * kH + k0 + q * 4];
    asm volatile("" : "+v"(ua[q].x), "+v"(ua[q].y), "+v"(ua[q].z), "+v"(ua[q].w));
    asm volatile("" : "+v"(uz[q].x), "+v"(uz[q].y), "+v"(uz[q].z), "+v"(uz[q].w));
  }

  const float* wrow = wn + (size_t)b * kT * kGG;
  float* hrow = hist + (size_t)b * kT * kH;

  const bool poller = (tid < 128);
  const bool loader = (tid >= 128) && (tid < 192);
  const int w0 = 4 * tid;                      // 4 h-words each poller owns
  const int lc = (w0 >> 6) * 68 + (w0 & 63);   // their LDS slot (16B aligned)

  // loader setup: gate column this loader owns; preload w(0)
  const int j2   = tid - 128;                                  // 0..63
  const int wcol = (j2 < 32) ? (jblk * 32 + j2)
                             : (kH + jblk * 32 + (j2 - 32));
  float wreg = 0.f;
  if (loader) wreg = wrow[wcol];   // w(0)

  float hprev = 0.f;   // h[b,j], carried by ks==0 lanes

  for (int t = 0; t < kT; ++t) {
    float* dst = hsh[t & 1];
    if (poller) {
      if (t == 0) {
        *(float4*)&dst[lc] = make_float4(0.f, 0.f, 0.f, 0.f);
      } else {
        const int* hp = (const int*)(hrow + (size_t)(t - 1) * kH) + w0;
        v4i v;
        poll_issue(hp, &v);
        poll_wait(&v);
        while ((v.x | v.y | v.z | v.w) < 0) {   // any sign bit set => retry
          poll_issue(hp, &v);
          poll_wait(&v);
        }
        float4 f;
        f.x = __int_as_float(v.x); f.y = __int_as_float(v.y);
        f.z = __int_as_float(v.z); f.w = __int_as_float(v.w);
        *(float4*)&dst[lc] = f;
      }
    }
    if (loader) {
      wsh[t & 1][j2] = wreg;                                   // deliver w(t)
      if (t + 1 < kT) wreg = wrow[(size_t)(t + 1) * kGG + wcol];  // prefetch
    }
    __syncthreads();   // h(t-1) + w(t) staged

    const float* src = dst + ks * 68;
    float ga = 0.f, gz = 0.f;
#pragma unroll
    for (int q = 0; q < 16; ++q) {
      const float4 h4 = *(const float4*)&src[q * 4];
      ga += h4.x * ua[q].x + h4.y * ua[q].y + h4.z * ua[q].z + h4.w * ua[q].w;
      gz += h4.x * uz[q].x + h4.y * uz[q].y + h4.z * uz[q].z + h4.w * uz[q].w;
    }
#pragma unroll
    for (int off = 1; off < 8; off <<= 1) {
      ga += __shfl_xor(ga, off);
      gz += __shfl_xor(gz, off);
    }

    if (ks == 0) {
      const float a    = wsh[t & 1][jj] + ga;
      const float z    = wsh[t & 1][32 + jj] + gz;
      const float zt   = 1.f / (1.f + __expf(-z));
      const float hc   = fmaxf(a, 0.f);
      const float hnew = zt * hprev + (1.f - zt) * hc;
      hprev = hnew;
      // agent-scope write-through: LLC-visible, placement-independent
      __hip_atomic_store((int*)&hrow[(size_t)t * kH + j], __float_as_int(hnew),
                         __ATOMIC_RELAXED, __HIP_MEMORY_SCOPE_AGENT);
    }
    // next iteration uses the other LDS buffers; its __syncthreads orders
    // those writes against this step's reads (no trailing barrier needed).
  }
}

// ---------------------------------------------------------------------------
extern "C" void kernel_launch(void* const* d_in, const int* in_sizes, int n_in,
                              void* d_out, int out_size, void* d_ws,
                              size_t ws_size, hipStream_t stream) {
  const float* x  = (const float*)d_in[0];
  const float* W0 = (const float*)d_in[1];
  const float* U0 = (const float*)d_in[2];
  const float* g0 = (const float*)d_in[3];
  const float* b0 = (const float*)d_in[4];
  const float* W1 = (const float*)d_in[5];
  const float* U1 = (const float*)d_in[6];
  const float* g1 = (const float*)d_in[7];
  const float* b1 = (const float*)d_in[8];
  float* out = (float*)d_out;

  float* w = (float*)d_ws;   // 24000*1024 floats (98.3MB)

  const size_t out_bytes = (size_t)kM * kH * sizeof(float);   // 49.2MB

  // ---------------- layer 0 ----------------
  hipMemsetAsync(out, 0xFF, out_bytes, stream);   // poison = "not ready"
  gemm_nt_k<<<dim3(kM / 64, kGG / 64), 256, 0, stream>>>(x, W0, w, kF);
  ln_rows<<<kM, 256, 0, stream>>>(w, g0, b0);
  {
    const float* wn_p = w;
    const float* U_p  = U0;
    float* h_p = out;                 // layer-0 h history == GEMM2 input
    void* args[] = {&wn_p, &U_p, &h_p};
    hipLaunchCooperativeKernel((const void*)ligru_scan, dim3(256), dim3(256),
                               args, 0, stream);
  }

  // ---------------- layer 1 ----------------
  gemm_nt_k<<<dim3(kM / 64, kGG / 64), 256, 0, stream>>>(out, W1, w, kH);
  ln_rows<<<kM, 256, 0, stream>>>(w, g1, b1);
  hipMemsetAsync(out, 0xFF, out_bytes, stream);   // re-poison for layer 1
  {
    const float* wn_p = w;
    const float* U_p  = U1;
    float* h_p = out;                 // final output
    void* args[] = {&wn_p, &U_p, &h_p};
    hipLaunchCooperativeKernel((const void*)ligru_scan, dim3(256), dim3(256),
                               args, 0, stream);
  }
}

// Round 13
// 4893.505 us; speedup vs baseline: 1.4653x; 1.4653x over previous
//
#include <hip/hip_runtime.h>
#include <cstddef>
#include <cstdint>

#define kB 16
#define kT 1500
#define kF 80
#define kH 512
#define kGG 1024
#define kM (kB * kT)

typedef int v4i __attribute__((ext_vector_type(4)));

// Deep poll, split issue/wait. sc0 sc1 = system scope: bypasses L1+L2, reads
// LLC truth — guaranteed progress regardless of block->XCD placement.
__device__ __forceinline__ void poll_issue(const int* p, v4i* v) {
  asm volatile("global_load_dwordx4 %0, %1, off sc0 sc1"
               : "=v"(*v) : "v"(p) : "memory");
}
__device__ __forceinline__ void poll_wait(v4i* v) {
  asm volatile("s_waitcnt vmcnt(0)" : "+v"(*v) :: "memory");
}

// ---------------------------------------------------------------------------
// GEMM: C(M,1024) = A(M,K) @ Bt(1024,K)^T   (all row-major, fp32)
// ---------------------------------------------------------------------------
__global__ __launch_bounds__(256) void gemm_nt_k(
    const float* __restrict__ A, const float* __restrict__ Bt,
    float* __restrict__ C, int K) {
  __shared__ float As[16][68];
  __shared__ float Bs[16][68];
  const int tid = threadIdx.x;
  const int m0 = blockIdx.x * 64;
  const int n0 = blockIdx.y * 64;
  const int tx = tid & 15;
  const int ty = tid >> 4;
  const int r  = tid >> 2;
  const int q  = tid & 3;
  float acc[4][4] = {};
  for (int k0 = 0; k0 < K; k0 += 16) {
    const float4 va = *(const float4*)&A [(size_t)(m0 + r) * K + k0 + q * 4];
    const float4 vb = *(const float4*)&Bt[(size_t)(n0 + r) * K + k0 + q * 4];
    __syncthreads();
    As[q * 4 + 0][r] = va.x; As[q * 4 + 1][r] = va.y;
    As[q * 4 + 2][r] = va.z; As[q * 4 + 3][r] = va.w;
    Bs[q * 4 + 0][r] = vb.x; Bs[q * 4 + 1][r] = vb.y;
    Bs[q * 4 + 2][r] = vb.z; Bs[q * 4 + 3][r] = vb.w;
    __syncthreads();
#pragma unroll
    for (int kk = 0; kk < 16; ++kk) {
      const float4 a = *(const float4*)&As[kk][ty * 4];
      const float4 b = *(const float4*)&Bs[kk][tx * 4];
      acc[0][0] += a.x * b.x; acc[0][1] += a.x * b.y; acc[0][2] += a.x * b.z; acc[0][3] += a.x * b.w;
      acc[1][0] += a.y * b.x; acc[1][1] += a.y * b.y; acc[1][2] += a.y * b.z; acc[1][3] += a.y * b.w;
      acc[2][0] += a.z * b.x; acc[2][1] += a.z * b.y; acc[2][2] += a.z * b.z; acc[2][3] += a.z * b.w;
      acc[3][0] += a.w * b.x; acc[3][1] += a.w * b.y; acc[3][2] += a.w * b.z; acc[3][3] += a.w * b.w;
    }
  }
#pragma unroll
  for (int i = 0; i < 4; ++i) {
    float4 o;
    o.x = acc[i][0]; o.y = acc[i][1]; o.z = acc[i][2]; o.w = acc[i][3];
    *(float4*)&C[(size_t)(m0 + ty * 4 + i) * kGG + n0 + tx * 4] = o;
  }
}

// ---------------------------------------------------------------------------
// LayerNorm over rows of length 1024 (in place)
// ---------------------------------------------------------------------------
__global__ __launch_bounds__(256) void ln_rows(
    float* __restrict__ w, const float* __restrict__ g,
    const float* __restrict__ bb) {
  const int row = blockIdx.x;
  float4* p = (float4*)(w + (size_t)row * kGG);
  const int tid = threadIdx.x;
  float4 v = p[tid];
  float s  = v.x + v.y + v.z + v.w;
  float s2 = v.x * v.x + v.y * v.y + v.z * v.z + v.w * v.w;
#pragma unroll
  for (int off = 32; off >= 1; off >>= 1) {
    s  += __shfl_down(s, off);
    s2 += __shfl_down(s2, off);
  }
  __shared__ float red[8];
  const int lane = tid & 63, wv = tid >> 6;
  if (lane == 0) { red[wv] = s; red[4 + wv] = s2; }
  __syncthreads();
  s  = red[0] + red[1] + red[2] + red[3];
  s2 = red[4] + red[5] + red[6] + red[7];
  const float mu  = s * (1.f / kGG);
  const float var = s2 * (1.f / kGG) - mu * mu;
  const float rs  = rsqrtf(var + 1e-5f);
  const float4 gg = ((const float4*)g)[tid];
  const float4 bv = ((const float4*)bb)[tid];
  v.x = (v.x - mu) * rs * gg.x + bv.x;
  v.y = (v.y - mu) * rs * gg.y + bv.y;
  v.z = (v.z - mu) * rs * gg.z + bv.z;
  v.w = (v.w - mu) * rs * gg.w + bv.w;
  p[tid] = v;
}

// ---------------------------------------------------------------------------
// LiGRU scan, barrier-free producer/consumer (round-5 proven).
// h >= 0 invariant => sign-bit-set == "not yet written" (hist poisoned 0xFF).
// Producers: agent-scope relaxed stores (always LLC-visible).
// Consumers: 128 poller threads, one dwordx4 system-scope poll each (sc0 sc1,
// LLC truth — placement-independent), staged to padded LDS, one syncthreads.
// U slice pinned in VGPRs/AGPRs via opaque asm.
// ---------------------------------------------------------------------------
__global__ __launch_bounds__(256, 1) void ligru_scan(
    const float* __restrict__ wn,   // (B*T, 1024) normalized pre-gates
    const float* __restrict__ U,    // (1024, 512)
    float* __restrict__ hist) {     // (B, T, 512) h history == layer output
  const int blk  = blockIdx.x;
  const int b    = blk & 15;     // XCD-colocating decode (heuristic only)
  const int jblk = blk >> 4;
  const int tid  = threadIdx.x;
  const int ks   = tid & 7;
  const int jj   = tid >> 3;
  const int j    = jblk * 32 + jj;
  const int k0   = ks * 64;

  __shared__ float hsh[2][8 * 68];   // stride 68 -> conflict-free b128 reads

  // ---- U slice pinned in registers ----
  float4 ua[16], uz[16];
#pragma unroll
  for (int q = 0; q < 16; ++q) {
    ua[q] = *(const float4*)&U[(size_t)j * kH + k0 + q * 4];
    uz[q] = *(const float4*)&U[(size_t)(j + kH) * kH + k0 + q * 4];
    asm volatile("" : "+v"(ua[q].x), "+v"(ua[q].y), "+v"(ua[q].z), "+v"(ua[q].w));
    asm volatile("" : "+v"(uz[q].x), "+v"(uz[q].y), "+v"(uz[q].z), "+v"(uz[q].w));
  }

  const float* wrow = wn + (size_t)b * kT * kGG;
  float* hrow = hist + (size_t)b * kT * kH;

  const bool poller = (tid < 128);
  const int w0 = 4 * tid;                      // 4 h-words each poller owns
  const int lc = (w0 >> 6) * 68 + (w0 & 63);   // their LDS slot (float4-safe)

  float hprev = 0.f;   // h[b,j], carried by ks==0 lanes

  for (int t = 0; t < kT; ++t) {
    float* dst = hsh[t & 1];
    if (poller) {
      if (t == 0) {
        *(float4*)&dst[lc] = make_float4(0.f, 0.f, 0.f, 0.f);
      } else {
        const int* hp = (const int*)(hrow + (size_t)(t - 1) * kH) + w0;
        v4i v;
        poll_issue(hp, &v);
        poll_wait(&v);
        while ((v.x | v.y | v.z | v.w) < 0) {   // any sign bit set => retry
          poll_issue(hp, &v);
          poll_wait(&v);
        }
        float4 f;
        f.x = __int_as_float(v.x); f.y = __int_as_float(v.y);
        f.z = __int_as_float(v.z); f.w = __int_as_float(v.w);
        *(float4*)&dst[lc] = f;
      }
    }
    __syncthreads();   // h(t-1) staged in LDS buffer t&1

    // w prefetch AFTER the poll (so poll's vmcnt(0) never drains it);
    // its latency hides under the dot below (compiler waits at use).
    float wa = 0.f, wz = 0.f;
    if (ks == 0) {
      wa = wrow[(size_t)t * kGG + j];
      wz = wrow[(size_t)t * kGG + kH + j];
    }

    const float* src = dst + ks * 68;
    float ga = 0.f, gz = 0.f;
#pragma unroll
    for (int q = 0; q < 16; ++q) {
      const float4 h4 = *(const float4*)&src[q * 4];
      ga += h4.x * ua[q].x + h4.y * ua[q].y + h4.z * ua[q].z + h4.w * ua[q].w;
      gz += h4.x * uz[q].x + h4.y * uz[q].y + h4.z * uz[q].z + h4.w * uz[q].w;
    }
#pragma unroll
    for (int off = 1; off < 8; off <<= 1) {
      ga += __shfl_xor(ga, off);
      gz += __shfl_xor(gz, off);
    }

    if (ks == 0) {
      const float a    = wa + ga;
      const float z    = wz + gz;
      const float zt   = 1.f / (1.f + __expf(-z));
      const float hc   = fmaxf(a, 0.f);
      const float hnew = zt * hprev + (1.f - zt) * hc;
      hprev = hnew;
      // agent-scope write-through: LLC-visible, placement-independent
      __hip_atomic_store((int*)&hrow[(size_t)t * kH + j], __float_as_int(hnew),
                         __ATOMIC_RELAXED, __HIP_MEMORY_SCOPE_AGENT);
    }
    // next iteration uses the other LDS buffer; its __syncthreads orders
    // those writes against this step's reads.
  }
}

// ---------------------------------------------------------------------------
extern "C" void kernel_launch(void* const* d_in, const int* in_sizes, int n_in,
                              void* d_out, int out_size, void* d_ws,
                              size_t ws_size, hipStream_t stream) {
  const float* x  = (const float*)d_in[0];
  const float* W0 = (const float*)d_in[1];
  const float* U0 = (const float*)d_in[2];
  const float* g0 = (const float*)d_in[3];
  const float* b0 = (const float*)d_in[4];
  const float* W1 = (const float*)d_in[5];
  const float* U1 = (const float*)d_in[6];
  const float* g1 = (const float*)d_in[7];
  const float* b1 = (const float*)d_in[8];
  float* out = (float*)d_out;

  float* w = (float*)d_ws;   // 24000*1024 floats (98.3MB)

  const size_t out_bytes = (size_t)kM * kH * sizeof(float);   // 49.2MB

  // ---------------- layer 0 ----------------
  hipMemsetAsync(out, 0xFF, out_bytes, stream);   // poison = "not ready"
  gemm_nt_k<<<dim3(kM / 64, kGG / 64), 256, 0, stream>>>(x, W0, w, kF);
  ln_rows<<<kM, 256, 0, stream>>>(w, g0, b0);
  {
    const float* wn_p = w;
    const float* U_p  = U0;
    float* h_p = out;                 // layer-0 h history == GEMM2 input
    void* args[] = {&wn_p, &U_p, &h_p};
    hipLaunchCooperativeKernel((const void*)ligru_scan, dim3(256), dim3(256),
                               args, 0, stream);
  }

  // ---------------- layer 1 ----------------
  gemm_nt_k<<<dim3(kM / 64, kGG / 64), 256, 0, stream>>>(out, W1, w, kH);
  ln_rows<<<kM, 256, 0, stream>>>(w, g1, b1);
  hipMemsetAsync(out, 0xFF, out_bytes, stream);   // re-poison for layer 1
  {
    const float* wn_p = w;
    const float* U_p  = U1;
    float* h_p = out;                 // final output
    void* args[] = {&wn_p, &U_p, &h_p};
    hipLaunchCooperativeKernel((const void*)ligru_scan, dim3(256), dim3(256),
                               args, 0, stream);
  }
}